// Round 9
// baseline (203.005 us; speedup 1.0000x reference)
//
#include <hip/hip_runtime.h>
#include <hip/hip_bf16.h>

#define DMODEL 1024
#define NH     16
#define DKH    64
#define BSZ    2
#define SEQ    2048
#define MROWS  (BSZ*SEQ)      // 4096
#define WELEM  (DMODEL*DMODEL)

typedef __attribute__((ext_vector_type(8))) short short8;
typedef __attribute__((ext_vector_type(4))) short short4v;
typedef __attribute__((ext_vector_type(4))) float f32x4;

// Legacy K=16 bf16 MFMA (gfx950 ISA table: v_mfma_f32_16x16x16_bf16, 2-VGPR
// A/B). Its A-frag layout (lane: row l&15, k=(l>>4)*4+{0..3}) matches the
// swapped-QK^T score layout EXACTLY -> PV consumes P from registers.
// R3 lesson: __has_builtin(amdgcn builtin) is FALSE in the HIP host pass —
// guard with __HIP_DEVICE_COMPILE__ and give the host a parse-only stub.
__device__ __forceinline__ f32x4 mfma_pv16(short4v a, short4v b, f32x4 c) {
#if defined(__HIP_DEVICE_COMPILE__)
#if __has_builtin(__builtin_amdgcn_mfma_f32_16x16x16bf16_1k)
    return __builtin_amdgcn_mfma_f32_16x16x16bf16_1k(a, b, c, 0, 0, 0);
#elif __has_builtin(__builtin_amdgcn_mfma_f32_16x16x16_bf16)
    return __builtin_amdgcn_mfma_f32_16x16x16_bf16(a, b, c, 0, 0, 0);
#else
    f32x4 d;
    asm volatile("v_mfma_f32_16x16x16_bf16 %0, %1, %2, %3"
                 : "=v"(d) : "v"(a), "v"(b), "v"(c));
    return d;
#endif
#else
    (void)a; (void)b;
    return c;   // host stub — never executed
#endif
}

__device__ __forceinline__ ushort f2bf(float f) {
    return __bfloat16_as_ushort(__float2bfloat16(f));
}
__device__ __forceinline__ unsigned pk2(float lo, float hi) {
    return (unsigned)f2bf(lo) | ((unsigned)f2bf(hi) << 16);
}
// Async global->LDS, 16 B/lane. LDS dest = wave-uniform base + lane*16
// (m97-validated). Global address may be arbitrary per-lane.
__device__ __forceinline__ void load_lds16(const ushort* g, ushort* l) {
    __builtin_amdgcn_global_load_lds(
        (const __attribute__((address_space(1))) unsigned int*)g,
        (__attribute__((address_space(3))) unsigned int*)l, 16, 0, 0);
}

// Merged fp32->bf16 conversion (R17-validated).
__global__ __launch_bounds__(256)
void cvt_all(const float* __restrict__ x,
             const float* __restrict__ W0, const float* __restrict__ W1,
             const float* __restrict__ W2, const float* __restrict__ W3,
             ushort* __restrict__ xbf, ushort* __restrict__ Wcat,
             ushort* __restrict__ Wo)
{
    const int blk = blockIdx.x;
    const float* src;
    ushort* dst;
    int base;
    if (blk < 2048)      { src = x;  dst = xbf;             base = blk * 2048; }
    else if (blk < 2560) { src = W0; dst = Wcat;            base = (blk - 2048) * 2048; }
    else if (blk < 3072) { src = W1; dst = Wcat + WELEM;    base = (blk - 2560) * 2048; }
    else if (blk < 3584) { src = W2; dst = Wcat + 2*WELEM;  base = (blk - 3072) * 2048; }
    else                 { src = W3; dst = Wo;              base = (blk - 3584) * 2048; }
    const size_t off = (size_t)base + threadIdx.x * 8;
    const float4 f0 = *(const float4*)(src + off);
    const float4 f1 = *(const float4*)(src + off + 4);
    uint4 o;
    o.x = pk2(f0.x, f0.y); o.y = pk2(f0.z, f0.w);
    o.z = pk2(f1.x, f1.y); o.w = pk2(f1.z, f1.w);
    *(uint4*)(dst + off) = o;
}

// FUSED QKV GEMM, m97-style async staging: unpadded LDS, global_load_lds x4
// per thread per BK-iter. BK=32 single-buffer, 2 barriers/iter — VERIFIED
// optimum structure (44.4 us). R6 (BK=64) / R7 (dbuf) both regressed.
// R9: XCD-aware block swizzle (T1). Default dispatch round-robins adjacent
// blocks across 8 XCDs -> each XCD streams all of xbf+Wcat (15 MB) through
// its 4 MB L2 -> staging drains pay HBM-miss latency (~900 cy). Remap so
// each XCD owns a 12n x 8m super-tile: footprint ~3 MB W-panel + ~2 MB
// x-panel ~= L2 -> drains become L2 hits (~200 cy). Bijective: 768 = 8*96.
// Region 0 (Q) PRE-SCALED by (1/8)*log2(e) for exp2 softmax.
__global__ __launch_bounds__(256)
void gemm_qkv(const ushort* __restrict__ xbf, const ushort* __restrict__ Wcat,
              const float* __restrict__ bq, const float* __restrict__ bk,
              const float* __restrict__ bv,
              ushort* __restrict__ Qh, ushort* __restrict__ Kh,
              ushort* __restrict__ VT)
{
    __shared__ ushort Ash[128][32];   // packed: rows = 64 B, lane-contiguous
    __shared__ ushort Bsh[128][32];

    const int t    = threadIdx.x;
    // XCD swizzle: bid -> (xcd, cell) -> 12n x 8m region per XCD
    const int bid  = blockIdx.y * 24 + blockIdx.x;   // grid (24, 32)
    const int xcd  = bid & 7;
    const int c    = bid >> 3;                       // 0..95
    const int n0   = ((xcd & 1) * 12 + (c % 12)) * 128;
    const int m0   = ((xcd >> 1) * 8 + (c / 12)) * 128;

    const int wave = t >> 6;
    const int lane = t & 63;
    const int wr   = (wave >> 1) * 64;
    const int wc   = (wave & 1) * 64;
    const int quad = lane >> 4;
    const int r16  = lane & 15;

    const int row0 = wave * 16 + (lane >> 2);
    const int row1 = 64 + wave * 16 + (lane >> 2);
    const int ch   = (lane & 3) * 8;

    f32x4 acc[4][4];
    #pragma unroll
    for (int i = 0; i < 4; ++i)
        #pragma unroll
        for (int j = 0; j < 4; ++j)
            acc[i][j] = (f32x4){0.f, 0.f, 0.f, 0.f};

    for (int k0 = 0; k0 < DMODEL; k0 += 32) {
        load_lds16(xbf  + (size_t)(m0 + row0) * DMODEL + k0 + ch, &Ash[wave * 16][0]);
        load_lds16(xbf  + (size_t)(m0 + row1) * DMODEL + k0 + ch, &Ash[64 + wave * 16][0]);
        load_lds16(Wcat + (size_t)(n0 + row0) * DMODEL + k0 + ch, &Bsh[wave * 16][0]);
        load_lds16(Wcat + (size_t)(n0 + row1) * DMODEL + k0 + ch, &Bsh[64 + wave * 16][0]);
        __syncthreads();

        short8 af[4], bf[4];
        #pragma unroll
        for (int i = 0; i < 4; ++i) af[i] = *(const short8*)&Ash[wr + i * 16 + r16][quad * 8];
        #pragma unroll
        for (int j = 0; j < 4; ++j) bf[j] = *(const short8*)&Bsh[wc + j * 16 + r16][quad * 8];

        #pragma unroll
        for (int i = 0; i < 4; ++i)
            #pragma unroll
            for (int j = 0; j < 4; ++j)
                acc[i][j] = __builtin_amdgcn_mfma_f32_16x16x32_bf16(af[i], bf[j], acc[i][j], 0, 0, 0);
        __syncthreads();
    }

    const int region = n0 >> 10;
    const float* bp  = (region == 0) ? bq : (region == 1) ? bk : bv;
    ushort* outQK    = (region == 0) ? Qh : Kh;
    // 0.125 * log2(e): fold the exp->exp2 conversion into the Q pre-scale.
    const float osc  = (region == 0) ? 0.18033688f : 1.0f;
    const int nbase  = n0 & 1023;

    #pragma unroll
    for (int i = 0; i < 4; ++i) {
        #pragma unroll
        for (int j = 0; j < 4; ++j) {
            #pragma unroll
            for (int reg = 0; reg < 4; ++reg) {
                const int m  = m0 + wr + i * 16 + quad * 4 + reg;
                const int n  = nbase + wc + j * 16 + r16;
                const float v = (acc[i][j][reg] + bp[n]) * osc;
                const int b = m >> 11, s = m & (SEQ - 1);
                const int h = n >> 6,  dk = n & 63;
                if (region < 2) {
                    outQK[((size_t)(b * NH + h) * SEQ + s) * DKH + dk] = f2bf(v);
                } else {
                    VT[(((size_t)(b * NH + h)) * DKH + dk) * SEQ + s] = f2bf(v);
                }
            }
        }
    }
}

// Output projection with async staging. O bf16 head-major; out fp32 row-major.
// Tile 128x64 -> 512 blocks. BK=32 single-buffer (verified).
// R9: XCD swizzle, 8n x 8m regions per XCD (footprint ~1 MB Wo-panel +
// ~2 MB O-panel ~= L2). Bijective: 512 = 8*64.
__global__ __launch_bounds__(256)
void gemm_out(const ushort* __restrict__ O, const ushort* __restrict__ Wo,
              const float* __restrict__ bo, float* __restrict__ out)
{
    __shared__ ushort Ash[128][32];
    __shared__ ushort Bsh[64][32];

    const int t    = threadIdx.x;
    const int bid  = blockIdx.y * 16 + blockIdx.x;   // grid (16, 32)
    const int xcd  = bid & 7;
    const int c    = bid >> 3;                       // 0..63
    const int n0   = ((xcd & 1) * 8 + (c % 8)) * 64;
    const int m0   = ((xcd >> 1) * 8 + (c / 8)) * 128;

    const int wave = t >> 6;
    const int lane = t & 63;
    const int wr   = (wave >> 1) * 64;
    const int wc   = (wave & 1) * 32;
    const int quad = lane >> 4;
    const int r16  = lane & 15;

    const int row0 = wave * 16 + (lane >> 2);
    const int row1 = 64 + wave * 16 + (lane >> 2);
    const int ch   = (lane & 3) * 8;

    f32x4 acc[4][2];
    #pragma unroll
    for (int i = 0; i < 4; ++i)
        #pragma unroll
        for (int j = 0; j < 2; ++j)
            acc[i][j] = (f32x4){0.f, 0.f, 0.f, 0.f};

    for (int k0 = 0; k0 < DMODEL; k0 += 32) {
        const int ma0 = m0 + row0, ma1 = m0 + row1;
        load_lds16(O + ((size_t)(ma0 >> 11) * NH + (k0 >> 6)) * (SEQ * DKH)
                     + (size_t)(ma0 & (SEQ - 1)) * DKH + (k0 & 63) + ch,
                   &Ash[wave * 16][0]);
        load_lds16(O + ((size_t)(ma1 >> 11) * NH + (k0 >> 6)) * (SEQ * DKH)
                     + (size_t)(ma1 & (SEQ - 1)) * DKH + (k0 & 63) + ch,
                   &Ash[64 + wave * 16][0]);
        load_lds16(Wo + (size_t)(n0 + row0) * DMODEL + k0 + ch, &Bsh[wave * 16][0]);
        __syncthreads();

        short8 af[4], bf[2];
        #pragma unroll
        for (int i = 0; i < 4; ++i) af[i] = *(const short8*)&Ash[wr + i * 16 + r16][quad * 8];
        #pragma unroll
        for (int j = 0; j < 2; ++j) bf[j] = *(const short8*)&Bsh[wc + j * 16 + r16][quad * 8];

        #pragma unroll
        for (int i = 0; i < 4; ++i)
            #pragma unroll
            for (int j = 0; j < 2; ++j)
                acc[i][j] = __builtin_amdgcn_mfma_f32_16x16x32_bf16(af[i], bf[j], acc[i][j], 0, 0, 0);
        __syncthreads();
    }

    #pragma unroll
    for (int i = 0; i < 4; ++i) {
        #pragma unroll
        for (int j = 0; j < 2; ++j) {
            #pragma unroll
            for (int reg = 0; reg < 4; ++reg) {
                const int m = m0 + wr + i * 16 + quad * 4 + reg;
                const int n = n0 + wc + j * 16 + r16;
                out[(size_t)m * DMODEL + n] = acc[i][j][reg] + bo[n];
            }
        }
    }
}

// Generic MFMA GEMM — low-ws fallback only (R13/R14-validated).
__global__ __launch_bounds__(256)
void gemm_mfma(const void* __restrict__ A, const void* __restrict__ W,
               const float* __restrict__ bias, void* __restrict__ out,
               int amode, int bmode, int outmode, float oscale)
{
    __shared__ ushort Ash[128][40];
    __shared__ ushort Bsh[128][40];

    const int t    = threadIdx.x;
    const int m0   = blockIdx.y * 128, n0 = blockIdx.x * 128;
    const int srow = t >> 1;
    const int shal = (t & 1) * 16;

    const int wave = t >> 6;
    const int lane = t & 63;
    const int wr   = (wave >> 1) * 64;
    const int wc   = (wave & 1) * 64;
    const int quad = lane >> 4;
    const int r16  = lane & 15;

    f32x4 acc[4][4];
    #pragma unroll
    for (int i = 0; i < 4; ++i)
        #pragma unroll
        for (int j = 0; j < 4; ++j)
            acc[i][j] = (f32x4){0.f, 0.f, 0.f, 0.f};

    for (int k0 = 0; k0 < DMODEL; k0 += 32) {
        uint4 a01, a23, b01, b23;
        if (amode == 0) {
            const float* ap = (const float*)A + (size_t)(m0 + srow) * DMODEL + k0 + shal;
            const float4 f0 = *(const float4*)(ap);
            const float4 f1 = *(const float4*)(ap + 4);
            const float4 f2 = *(const float4*)(ap + 8);
            const float4 f3 = *(const float4*)(ap + 12);
            a01 = (uint4){pk2(f0.x,f0.y), pk2(f0.z,f0.w), pk2(f1.x,f1.y), pk2(f1.z,f1.w)};
            a23 = (uint4){pk2(f2.x,f2.y), pk2(f2.z,f2.w), pk2(f3.x,f3.y), pk2(f3.z,f3.w)};
        } else if (amode == 1) {
            const int m = m0 + srow;
            const ushort* ap = (const ushort*)A
                + ((size_t)(m >> 11) * NH + (k0 >> 6)) * (SEQ * DKH)
                + (size_t)(m & (SEQ - 1)) * DKH + (k0 & 63) + shal;
            a01 = *(const uint4*)(ap);
            a23 = *(const uint4*)(ap + 8);
        } else {
            const ushort* ap = (const ushort*)A + (size_t)(m0 + srow) * DMODEL + k0 + shal;
            a01 = *(const uint4*)(ap);
            a23 = *(const uint4*)(ap + 8);
        }
        if (bmode == 0) {
            const float* wp = (const float*)W + (size_t)(n0 + srow) * DMODEL + k0 + shal;
            const float4 w0 = *(const float4*)(wp);
            const float4 w1 = *(const float4*)(wp + 4);
            const float4 w2 = *(const float4*)(wp + 8);
            const float4 w3 = *(const float4*)(wp + 12);
            b01 = (uint4){pk2(w0.x,w0.y), pk2(w0.z,w0.w), pk2(w1.x,w1.y), pk2(w1.z,w1.w)};
            b23 = (uint4){pk2(w2.x,w2.y), pk2(w2.z,w2.w), pk2(w3.x,w3.y), pk2(w3.z,w3.w)};
        } else {
            const ushort* wp = (const ushort*)W + (size_t)(n0 + srow) * DMODEL + k0 + shal;
            b01 = *(const uint4*)(wp);
            b23 = *(const uint4*)(wp + 8);
        }

        *(uint4*)&Ash[srow][shal]     = a01;
        *(uint4*)&Ash[srow][shal + 8] = a23;
        *(uint4*)&Bsh[srow][shal]     = b01;
        *(uint4*)&Bsh[srow][shal + 8] = b23;
        __syncthreads();

        short8 af[4], bf[4];
        #pragma unroll
        for (int i = 0; i < 4; ++i) af[i] = *(const short8*)&Ash[wr + i * 16 + r16][quad * 8];
        #pragma unroll
        for (int j = 0; j < 4; ++j) bf[j] = *(const short8*)&Bsh[wc + j * 16 + r16][quad * 8];

        #pragma unroll
        for (int i = 0; i < 4; ++i)
            #pragma unroll
            for (int j = 0; j < 4; ++j)
                acc[i][j] = __builtin_amdgcn_mfma_f32_16x16x32_bf16(af[i], bf[j], acc[i][j], 0, 0, 0);
        __syncthreads();
    }

    #pragma unroll
    for (int i = 0; i < 4; ++i) {
        #pragma unroll
        for (int j = 0; j < 4; ++j) {
            #pragma unroll
            for (int reg = 0; reg < 4; ++reg) {
                const int m = m0 + wr + i * 16 + quad * 4 + reg;
                const int n = n0 + wc + j * 16 + r16;
                const float v = (acc[i][j][reg] + bias[n]) * oscale;
                if (outmode == 0) {
                    ((float*)out)[(size_t)m * DMODEL + n] = v;
                } else if (outmode == 1) {
                    ((ushort*)out)[((size_t)(m >> 11) * NH + (n >> 6)) * (SEQ * DKH)
                                   + (size_t)(m & (SEQ - 1)) * DKH + (n & 63)] = f2bf(v);
                } else {
                    ((ushort*)out)[(((size_t)(m >> 11) * NH + (n >> 6)) * DKH + (n & 63)) * SEQ
                                   + (m & (SEQ - 1))] = f2bf(v);
                }
            }
        }
    }
}

// MFMA flash attention R20b (verified best): REGISTER-DIRECT PV via
// v_mfma_f32_16x16x16_bf16. Swapped-QK^T score layout IS the K=16 MFMA
// A-frag layout -> P never touches LDS. Carried: 512 thr / 128 q-rows, LPT,
// peeled diag, reg prefetch (T14), setprio (T5), exp2 w/ folded scale,
// XCD swizzle.
__global__ __launch_bounds__(512, 4)
void attn_flash(ushort* __restrict__ Qh,
                const ushort* __restrict__ Kh,
                const ushort* __restrict__ VT)
{
    __shared__ ushort Kl[128][72];      // 18432 B
    __shared__ ushort Vl[64][136];      // 17408 B

    const int t512 = threadIdx.x;
    const int wave = t512 >> 6;          // 0..7
    const int lane = t512 & 63;
    const int quad = lane >> 4;
    const int r16  = lane & 15;

    // XCD swizzle (same-head blocks share blockIdx&7) + LPT (heavy qt first)
    const int slot = blockIdx.x & 7;
    const int bh   = slot * 4 + ((blockIdx.x >> 3) & 3);
    const int qt   = 15 - (blockIdx.x >> 5);
    const int q0   = qt * 128;

    ushort*       Qbase = Qh + (size_t)bh * SEQ * DKH;
    const ushort* Kbase = Kh + (size_t)bh * SEQ * DKH;
    const ushort* Vbase = VT + (size_t)bh * DKH * SEQ;

    short8 qf[2];
    {
        const ushort* qrow = Qbase + (size_t)(q0 + wave * 16 + r16) * DKH;
        qf[0] = *(const short8*)(qrow + quad * 8);
        qf[1] = *(const short8*)(qrow + 32 + quad * 8);
    }

    f32x4 oacc[4];
    #pragma unroll
    for (int i = 0; i < 4; ++i) oacc[i] = (f32x4){0.f, 0.f, 0.f, 0.f};
    f32x4 lsum4 = (f32x4){0.f, 0.f, 0.f, 0.f};

    const int T    = qt + 1;            // 128-row q-tile aligns with 128-col k-tiles
    const int qrel = wave * 16 + r16;   // q row relative to diag-tile start

    // staging: K 128x64 (16 KB), V 64x128 (16 KB); 32 B per thread each
    const int krow = t512 >> 2, kc = (t512 & 3) * 16;
    const int vrow = t512 >> 3, vc = (t512 & 7) * 16;
    const ushort* kg0 = Kbase + (size_t)krow * DKH + kc;
    const ushort* vg0 = Vbase + (size_t)vrow * SEQ + vc;

    uint4 kr0, kr1, vr0, vr1;
    kr0 = *(const uint4*)(kg0);
    kr1 = *(const uint4*)(kg0 + 8);
    vr0 = *(const uint4*)(vg0);
    vr1 = *(const uint4*)(vg0 + 8);

    // ---------------- main loop: full tiles, mask-free ----------------
    for (int t = 0; t < T - 1; ++t) {
        *(uint4*)&Kl[krow][kc]     = kr0;
        *(uint4*)&Kl[krow][kc + 8] = kr1;
        *(uint4*)&Vl[vrow][vc]     = vr0;
        *(uint4*)&Vl[vrow][vc + 8] = vr1;
        __syncthreads();

        // prefetch next tile; lands during this tile's compute (T14)
        {
            const ushort* kg = kg0 + (size_t)(t + 1) * 128 * DKH;
            kr0 = *(const uint4*)(kg);
            kr1 = *(const uint4*)(kg + 8);
            const ushort* vg = vg0 + (size_t)(t + 1) * 128;
            vr0 = *(const uint4*)(vg);
            vr1 = *(const uint4*)(vg + 8);
        }

        #pragma unroll
        for (int nt = 0; nt < 8; ++nt) {
            // QK^T (swapped): s[reg] = S[k=nt*16+quad*4+reg][q=r16]
            short8 b0 = *(const short8*)&Kl[nt * 16 + r16][quad * 8];
            short8 b1 = *(const short8*)&Kl[nt * 16 + r16][32 + quad * 8];
            f32x4 s = (f32x4){0.f, 0.f, 0.f, 0.f};
            __builtin_amdgcn_s_setprio(1);
            s = __builtin_amdgcn_mfma_f32_16x16x32_bf16(b0, qf[0], s, 0, 0, 0);
            s = __builtin_amdgcn_mfma_f32_16x16x32_bf16(b1, qf[1], s, 0, 0, 0);
            __builtin_amdgcn_s_setprio(0);

            // softmax numerator, packed in-register (A-frag of K=16 MFMA)
            const float e0 = __builtin_amdgcn_exp2f(s[0]);
            const float e1 = __builtin_amdgcn_exp2f(s[1]);
            const float e2 = __builtin_amdgcn_exp2f(s[2]);
            const float e3 = __builtin_amdgcn_exp2f(s[3]);
            lsum4 += (f32x4){e0, e1, e2, e3};
            union { uint2 u; short4v s4; } pw;
            pw.u.x = pk2(e0, e1);
            pw.u.y = pk2(e2, e3);

            // PV: register-direct, K=16 per nt
            __builtin_amdgcn_s_setprio(1);
            #pragma unroll
            for (int ct = 0; ct < 4; ++ct) {
                short4v vb = *(const short4v*)&Vl[ct * 16 + r16][nt * 16 + quad * 4];
                oacc[ct] = mfma_pv16(pw.s4, vb, oacc[ct]);
            }
            __builtin_amdgcn_s_setprio(0);
        }
        __syncthreads();
    }

    // ---------------- peeled diagonal tile ----------------
    {
        *(uint4*)&Kl[krow][kc]     = kr0;
        *(uint4*)&Kl[krow][kc + 8] = kr1;
        *(uint4*)&Vl[vrow][vc]     = vr0;
        *(uint4*)&Vl[vrow][vc + 8] = vr1;
        __syncthreads();

        const int ntmax = wave | 1;     // k-cols touched: [0, (wave|1)*16+15]

        #pragma unroll
        for (int nt = 0; nt < 8; ++nt) {
            if (nt <= ntmax) {
                short8 b0 = *(const short8*)&Kl[nt * 16 + r16][quad * 8];
                short8 b1 = *(const short8*)&Kl[nt * 16 + r16][32 + quad * 8];
                f32x4 s = (f32x4){0.f, 0.f, 0.f, 0.f};
                __builtin_amdgcn_s_setprio(1);
                s = __builtin_amdgcn_mfma_f32_16x16x32_bf16(b0, qf[0], s, 0, 0, 0);
                s = __builtin_amdgcn_mfma_f32_16x16x32_bf16(b1, qf[1], s, 0, 0, 0);
                __builtin_amdgcn_s_setprio(0);

                float e0 = __builtin_amdgcn_exp2f(s[0]);
                float e1 = __builtin_amdgcn_exp2f(s[1]);
                float e2 = __builtin_amdgcn_exp2f(s[2]);
                float e3 = __builtin_amdgcn_exp2f(s[3]);
                const int kbase = nt * 16 + quad * 4;
                if (kbase + 0 > qrel) e0 = 0.f;
                if (kbase + 1 > qrel) e1 = 0.f;
                if (kbase + 2 > qrel) e2 = 0.f;
                if (kbase + 3 > qrel) e3 = 0.f;
                lsum4 += (f32x4){e0, e1, e2, e3};
                union { uint2 u; short4v s4; } pw;
                pw.u.x = pk2(e0, e1);
                pw.u.y = pk2(e2, e3);

                __builtin_amdgcn_s_setprio(1);
                #pragma unroll
                for (int ct = 0; ct < 4; ++ct) {
                    short4v vb = *(const short4v*)&Vl[ct * 16 + r16][nt * 16 + quad * 4];
                    oacc[ct] = mfma_pv16(pw.s4, vb, oacc[ct]);
                }
                __builtin_amdgcn_s_setprio(0);
            }
        }
        // no trailing barrier: nothing further touches LDS
    }

    // row-sum: lanes {r16, r16+16, r16+32, r16+48} hold partials for q-row r16
    float lsum = (lsum4[0] + lsum4[1]) + (lsum4[2] + lsum4[3]);
    lsum += __shfl_xor(lsum, 16, 64);
    lsum += __shfl_xor(lsum, 32, 64);

    #pragma unroll
    for (int reg = 0; reg < 4; ++reg) {
        // row sum for q-row (quad*4+reg) lives in lane (quad*4+reg)
        const float inv = 1.f / __shfl(lsum, quad * 4 + reg, 64);
        const int q = q0 + wave * 16 + quad * 4 + reg;
        ushort* orow = Qbase + (size_t)q * DKH;
        #pragma unroll
        for (int ct = 0; ct < 4; ++ct)
            orow[ct * 16 + r16] = f2bf(oacc[ct][reg] * inv);
    }
}

extern "C" void kernel_launch(void* const* d_in, const int* in_sizes, int n_in,
                              void* d_out, int out_size, void* d_ws, size_t ws_size,
                              hipStream_t stream)
{
    // Settled: documented dict order; inputs fp32; output fp32; mask unused;
    // ws >= 24 MiB.
    const float* x  = (const float*)d_in[0];
    const float* Wf[4] = {(const float*)d_in[2], (const float*)d_in[4],
                          (const float*)d_in[6], (const float*)d_in[8]};
    const float* Bf[4] = {(const float*)d_in[3], (const float*)d_in[5],
                          (const float*)d_in[7], (const float*)d_in[9]};

    const size_t HSZ = (size_t)MROWS * DMODEL;
    ushort* Qh = (ushort*)d_ws;
    ushort* Kh = (ushort*)d_out;
    ushort* VT = (ushort*)d_out + HSZ;

    const dim3 blk(256);

    if (ws_size >= 24u * 1024 * 1024) {
        ushort* Wcat = Qh + HSZ;
        ushort* Wo   = Wcat + 3 * (size_t)WELEM;
        ushort* xbf  = Wo + WELEM;

        cvt_all<<<dim3(4096), blk, 0, stream>>>(x, Wf[0], Wf[1], Wf[2], Wf[3],
                                                xbf, Wcat, Wo);

        gemm_qkv<<<dim3(3 * DMODEL / 128, MROWS / 128), blk, 0, stream>>>(
            xbf, Wcat, Bf[0], Bf[1], Bf[2], Qh, Kh, VT);

        attn_flash<<<dim3(BSZ * NH * 16), dim3(512), 0, stream>>>(Qh, Kh, VT);

        gemm_out<<<dim3(DMODEL / 64, MROWS / 128), blk, 0, stream>>>(
            Qh, Wo, Bf[3], (float*)d_out);
    } else {
        const dim3 gg(DMODEL / 128, MROWS / 128);
        gemm_mfma<<<gg, blk, 0, stream>>>(x, Wf[0], Bf[0], Qh, 0, 0, 1, 0.18033688f);
        gemm_mfma<<<gg, blk, 0, stream>>>(x, Wf[1], Bf[1], Kh, 0, 0, 1, 1.0f);
        gemm_mfma<<<gg, blk, 0, stream>>>(x, Wf[2], Bf[2], VT, 0, 0, 2, 1.0f);
        attn_flash<<<dim3(BSZ * NH * 16), dim3(512), 0, stream>>>(Qh, Kh, VT);
        gemm_mfma<<<gg, blk, 0, stream>>>(Qh, Wf[3], Bf[3], d_out, 1, 0, 0, 1.0f);
    }
}

// Round 10
// 196.626 us; speedup vs baseline: 1.0324x; 1.0324x over previous
//
#include <hip/hip_runtime.h>
#include <hip/hip_bf16.h>

#define DMODEL 1024
#define NH     16
#define DKH    64
#define BSZ    2
#define SEQ    2048
#define MROWS  (BSZ*SEQ)      // 4096
#define WELEM  (DMODEL*DMODEL)

typedef __attribute__((ext_vector_type(8))) short short8;
typedef __attribute__((ext_vector_type(4))) short short4v;
typedef __attribute__((ext_vector_type(4))) float f32x4;

// Legacy K=16 bf16 MFMA (gfx950 ISA table: v_mfma_f32_16x16x16_bf16, 2-VGPR
// A/B). Its A-frag layout (lane: row l&15, k=(l>>4)*4+{0..3}) matches the
// swapped-QK^T score layout EXACTLY -> PV consumes P from registers.
// R3 lesson: __has_builtin(amdgcn builtin) is FALSE in the HIP host pass —
// guard with __HIP_DEVICE_COMPILE__ and give the host a parse-only stub.
__device__ __forceinline__ f32x4 mfma_pv16(short4v a, short4v b, f32x4 c) {
#if defined(__HIP_DEVICE_COMPILE__)
#if __has_builtin(__builtin_amdgcn_mfma_f32_16x16x16bf16_1k)
    return __builtin_amdgcn_mfma_f32_16x16x16bf16_1k(a, b, c, 0, 0, 0);
#elif __has_builtin(__builtin_amdgcn_mfma_f32_16x16x16_bf16)
    return __builtin_amdgcn_mfma_f32_16x16x16_bf16(a, b, c, 0, 0, 0);
#else
    f32x4 d;
    asm volatile("v_mfma_f32_16x16x16_bf16 %0, %1, %2, %3"
                 : "=v"(d) : "v"(a), "v"(b), "v"(c));
    return d;
#endif
#else
    (void)a; (void)b;
    return c;   // host stub — never executed
#endif
}

__device__ __forceinline__ ushort f2bf(float f) {
    return __bfloat16_as_ushort(__float2bfloat16(f));
}
__device__ __forceinline__ unsigned pk2(float lo, float hi) {
    return (unsigned)f2bf(lo) | ((unsigned)f2bf(hi) << 16);
}
// Async global->LDS, 16 B/lane. LDS dest = wave-uniform base + lane*16
// (m97-validated). Global address may be arbitrary per-lane.
__device__ __forceinline__ void load_lds16(const ushort* g, ushort* l) {
    __builtin_amdgcn_global_load_lds(
        (const __attribute__((address_space(1))) unsigned int*)g,
        (__attribute__((address_space(3))) unsigned int*)l, 16, 0, 0);
}

// Merged fp32->bf16 conversion (R17-validated).
__global__ __launch_bounds__(256)
void cvt_all(const float* __restrict__ x,
             const float* __restrict__ W0, const float* __restrict__ W1,
             const float* __restrict__ W2, const float* __restrict__ W3,
             ushort* __restrict__ xbf, ushort* __restrict__ Wcat,
             ushort* __restrict__ Wo)
{
    const int blk = blockIdx.x;
    const float* src;
    ushort* dst;
    int base;
    if (blk < 2048)      { src = x;  dst = xbf;             base = blk * 2048; }
    else if (blk < 2560) { src = W0; dst = Wcat;            base = (blk - 2048) * 2048; }
    else if (blk < 3072) { src = W1; dst = Wcat + WELEM;    base = (blk - 2560) * 2048; }
    else if (blk < 3584) { src = W2; dst = Wcat + 2*WELEM;  base = (blk - 3072) * 2048; }
    else                 { src = W3; dst = Wo;              base = (blk - 3584) * 2048; }
    const size_t off = (size_t)base + threadIdx.x * 8;
    const float4 f0 = *(const float4*)(src + off);
    const float4 f1 = *(const float4*)(src + off + 4);
    uint4 o;
    o.x = pk2(f0.x, f0.y); o.y = pk2(f0.z, f0.w);
    o.z = pk2(f1.x, f1.y); o.w = pk2(f1.z, f1.w);
    *(uint4*)(dst + off) = o;
}

// FUSED QKV GEMM, m97-style async staging: unpadded LDS, global_load_lds x4
// per thread per BK-iter. BK=32 single-buffer, 2 barriers/iter — VERIFIED
// optimum structure for this kernel/harness (44.4 us, reproduced 3x).
// Structural plateau, documented evidence:
//   R6  BK=64 stacked      -> 64.0 us (LDS 32 KB halves residency)
//   R7  2-phase LDS dbuf   -> 71.7 us (compiler serializes src-level dbuf,
//                                      guide m99/m100 confirmed here)
//   R9  XCD block swizzle  -> 49.4 us (FETCH -43% but slower: default
//        bid%8 mapping already keeps each XCD's 3 Wcat column-panels
//        (768 KB) L2-resident; remap thrashes L2 with a ~4.4 MB set)
// Do not restructure without a race-screened 8-phase counted-vmcnt port
// AND a fix for the >16 KB-LDS residency cliff.
// Region 0 (Q) PRE-SCALED by (1/8)*log2(e) for exp2 softmax.
__global__ __launch_bounds__(256)
void gemm_qkv(const ushort* __restrict__ xbf, const ushort* __restrict__ Wcat,
              const float* __restrict__ bq, const float* __restrict__ bk,
              const float* __restrict__ bv,
              ushort* __restrict__ Qh, ushort* __restrict__ Kh,
              ushort* __restrict__ VT)
{
    __shared__ ushort Ash[128][32];   // packed: rows = 64 B, lane-contiguous
    __shared__ ushort Bsh[128][32];

    const int t    = threadIdx.x;
    const int m0   = blockIdx.y * 128, n0 = blockIdx.x * 128;
    const int wave = t >> 6;
    const int lane = t & 63;
    const int wr   = (wave >> 1) * 64;
    const int wc   = (wave & 1) * 64;
    const int quad = lane >> 4;
    const int r16  = lane & 15;

    const int row0 = wave * 16 + (lane >> 2);
    const int row1 = 64 + wave * 16 + (lane >> 2);
    const int ch   = (lane & 3) * 8;

    f32x4 acc[4][4];
    #pragma unroll
    for (int i = 0; i < 4; ++i)
        #pragma unroll
        for (int j = 0; j < 4; ++j)
            acc[i][j] = (f32x4){0.f, 0.f, 0.f, 0.f};

    for (int k0 = 0; k0 < DMODEL; k0 += 32) {
        load_lds16(xbf  + (size_t)(m0 + row0) * DMODEL + k0 + ch, &Ash[wave * 16][0]);
        load_lds16(xbf  + (size_t)(m0 + row1) * DMODEL + k0 + ch, &Ash[64 + wave * 16][0]);
        load_lds16(Wcat + (size_t)(n0 + row0) * DMODEL + k0 + ch, &Bsh[wave * 16][0]);
        load_lds16(Wcat + (size_t)(n0 + row1) * DMODEL + k0 + ch, &Bsh[64 + wave * 16][0]);
        __syncthreads();

        short8 af[4], bf[4];
        #pragma unroll
        for (int i = 0; i < 4; ++i) af[i] = *(const short8*)&Ash[wr + i * 16 + r16][quad * 8];
        #pragma unroll
        for (int j = 0; j < 4; ++j) bf[j] = *(const short8*)&Bsh[wc + j * 16 + r16][quad * 8];

        #pragma unroll
        for (int i = 0; i < 4; ++i)
            #pragma unroll
            for (int j = 0; j < 4; ++j)
                acc[i][j] = __builtin_amdgcn_mfma_f32_16x16x32_bf16(af[i], bf[j], acc[i][j], 0, 0, 0);
        __syncthreads();
    }

    const int region = n0 >> 10;
    const float* bp  = (region == 0) ? bq : (region == 1) ? bk : bv;
    ushort* outQK    = (region == 0) ? Qh : Kh;
    // 0.125 * log2(e): fold the exp->exp2 conversion into the Q pre-scale.
    const float osc  = (region == 0) ? 0.18033688f : 1.0f;
    const int nbase  = n0 & 1023;

    #pragma unroll
    for (int i = 0; i < 4; ++i) {
        #pragma unroll
        for (int j = 0; j < 4; ++j) {
            #pragma unroll
            for (int reg = 0; reg < 4; ++reg) {
                const int m  = m0 + wr + i * 16 + quad * 4 + reg;
                const int n  = nbase + wc + j * 16 + r16;
                const float v = (acc[i][j][reg] + bp[n]) * osc;
                const int b = m >> 11, s = m & (SEQ - 1);
                const int h = n >> 6,  dk = n & 63;
                if (region < 2) {
                    outQK[((size_t)(b * NH + h) * SEQ + s) * DKH + dk] = f2bf(v);
                } else {
                    VT[(((size_t)(b * NH + h)) * DKH + dk) * SEQ + s] = f2bf(v);
                }
            }
        }
    }
}

// Output projection with async staging. O bf16 head-major; out fp32 row-major.
// Tile 128x64 -> grid (16,32) = 512 blocks. BK=32 single-buffer (verified).
__global__ __launch_bounds__(256)
void gemm_out(const ushort* __restrict__ O, const ushort* __restrict__ Wo,
              const float* __restrict__ bo, float* __restrict__ out)
{
    __shared__ ushort Ash[128][32];
    __shared__ ushort Bsh[64][32];

    const int t    = threadIdx.x;
    const int m0   = blockIdx.y * 128, n0 = blockIdx.x * 64;
    const int wave = t >> 6;
    const int lane = t & 63;
    const int wr   = (wave >> 1) * 64;
    const int wc   = (wave & 1) * 32;
    const int quad = lane >> 4;
    const int r16  = lane & 15;

    const int row0 = wave * 16 + (lane >> 2);
    const int row1 = 64 + wave * 16 + (lane >> 2);
    const int ch   = (lane & 3) * 8;

    f32x4 acc[4][2];
    #pragma unroll
    for (int i = 0; i < 4; ++i)
        #pragma unroll
        for (int j = 0; j < 2; ++j)
            acc[i][j] = (f32x4){0.f, 0.f, 0.f, 0.f};

    for (int k0 = 0; k0 < DMODEL; k0 += 32) {
        const int ma0 = m0 + row0, ma1 = m0 + row1;
        load_lds16(O + ((size_t)(ma0 >> 11) * NH + (k0 >> 6)) * (SEQ * DKH)
                     + (size_t)(ma0 & (SEQ - 1)) * DKH + (k0 & 63) + ch,
                   &Ash[wave * 16][0]);
        load_lds16(O + ((size_t)(ma1 >> 11) * NH + (k0 >> 6)) * (SEQ * DKH)
                     + (size_t)(ma1 & (SEQ - 1)) * DKH + (k0 & 63) + ch,
                   &Ash[64 + wave * 16][0]);
        load_lds16(Wo + (size_t)(n0 + row0) * DMODEL + k0 + ch, &Bsh[wave * 16][0]);
        __syncthreads();

        short8 af[4], bf[2];
        #pragma unroll
        for (int i = 0; i < 4; ++i) af[i] = *(const short8*)&Ash[wr + i * 16 + r16][quad * 8];
        #pragma unroll
        for (int j = 0; j < 2; ++j) bf[j] = *(const short8*)&Bsh[wc + j * 16 + r16][quad * 8];

        #pragma unroll
        for (int i = 0; i < 4; ++i)
            #pragma unroll
            for (int j = 0; j < 2; ++j)
                acc[i][j] = __builtin_amdgcn_mfma_f32_16x16x32_bf16(af[i], bf[j], acc[i][j], 0, 0, 0);
        __syncthreads();
    }

    #pragma unroll
    for (int i = 0; i < 4; ++i) {
        #pragma unroll
        for (int j = 0; j < 2; ++j) {
            #pragma unroll
            for (int reg = 0; reg < 4; ++reg) {
                const int m = m0 + wr + i * 16 + quad * 4 + reg;
                const int n = n0 + wc + j * 16 + r16;
                out[(size_t)m * DMODEL + n] = acc[i][j][reg] + bo[n];
            }
        }
    }
}

// Generic MFMA GEMM — low-ws fallback only (R13/R14-validated).
__global__ __launch_bounds__(256)
void gemm_mfma(const void* __restrict__ A, const void* __restrict__ W,
               const float* __restrict__ bias, void* __restrict__ out,
               int amode, int bmode, int outmode, float oscale)
{
    __shared__ ushort Ash[128][40];
    __shared__ ushort Bsh[128][40];

    const int t    = threadIdx.x;
    const int m0   = blockIdx.y * 128, n0 = blockIdx.x * 128;
    const int srow = t >> 1;
    const int shal = (t & 1) * 16;

    const int wave = t >> 6;
    const int lane = t & 63;
    const int wr   = (wave >> 1) * 64;
    const int wc   = (wave & 1) * 64;
    const int quad = lane >> 4;
    const int r16  = lane & 15;

    f32x4 acc[4][4];
    #pragma unroll
    for (int i = 0; i < 4; ++i)
        #pragma unroll
        for (int j = 0; j < 4; ++j)
            acc[i][j] = (f32x4){0.f, 0.f, 0.f, 0.f};

    for (int k0 = 0; k0 < DMODEL; k0 += 32) {
        uint4 a01, a23, b01, b23;
        if (amode == 0) {
            const float* ap = (const float*)A + (size_t)(m0 + srow) * DMODEL + k0 + shal;
            const float4 f0 = *(const float4*)(ap);
            const float4 f1 = *(const float4*)(ap + 4);
            const float4 f2 = *(const float4*)(ap + 8);
            const float4 f3 = *(const float4*)(ap + 12);
            a01 = (uint4){pk2(f0.x,f0.y), pk2(f0.z,f0.w), pk2(f1.x,f1.y), pk2(f1.z,f1.w)};
            a23 = (uint4){pk2(f2.x,f2.y), pk2(f2.z,f2.w), pk2(f3.x,f3.y), pk2(f3.z,f3.w)};
        } else if (amode == 1) {
            const int m = m0 + srow;
            const ushort* ap = (const ushort*)A
                + ((size_t)(m >> 11) * NH + (k0 >> 6)) * (SEQ * DKH)
                + (size_t)(m & (SEQ - 1)) * DKH + (k0 & 63) + shal;
            a01 = *(const uint4*)(ap);
            a23 = *(const uint4*)(ap + 8);
        } else {
            const ushort* ap = (const ushort*)A + (size_t)(m0 + srow) * DMODEL + k0 + shal;
            a01 = *(const uint4*)(ap);
            a23 = *(const uint4*)(ap + 8);
        }
        if (bmode == 0) {
            const float* wp = (const float*)W + (size_t)(n0 + srow) * DMODEL + k0 + shal;
            const float4 w0 = *(const float4*)(wp);
            const float4 w1 = *(const float4*)(wp + 4);
            const float4 w2 = *(const float4*)(wp + 8);
            const float4 w3 = *(const float4*)(wp + 12);
            b01 = (uint4){pk2(w0.x,w0.y), pk2(w0.z,w0.w), pk2(w1.x,w1.y), pk2(w1.z,w1.w)};
            b23 = (uint4){pk2(w2.x,w2.y), pk2(w2.z,w2.w), pk2(w3.x,w3.y), pk2(w3.z,w3.w)};
        } else {
            const ushort* wp = (const ushort*)W + (size_t)(n0 + srow) * DMODEL + k0 + shal;
            b01 = *(const uint4*)(wp);
            b23 = *(const uint4*)(wp + 8);
        }

        *(uint4*)&Ash[srow][shal]     = a01;
        *(uint4*)&Ash[srow][shal + 8] = a23;
        *(uint4*)&Bsh[srow][shal]     = b01;
        *(uint4*)&Bsh[srow][shal + 8] = b23;
        __syncthreads();

        short8 af[4], bf[4];
        #pragma unroll
        for (int i = 0; i < 4; ++i) af[i] = *(const short8*)&Ash[wr + i * 16 + r16][quad * 8];
        #pragma unroll
        for (int j = 0; j < 4; ++j) bf[j] = *(const short8*)&Bsh[wc + j * 16 + r16][quad * 8];

        #pragma unroll
        for (int i = 0; i < 4; ++i)
            #pragma unroll
            for (int j = 0; j < 4; ++j)
                acc[i][j] = __builtin_amdgcn_mfma_f32_16x16x32_bf16(af[i], bf[j], acc[i][j], 0, 0, 0);
        __syncthreads();
    }

    #pragma unroll
    for (int i = 0; i < 4; ++i) {
        #pragma unroll
        for (int j = 0; j < 4; ++j) {
            #pragma unroll
            for (int reg = 0; reg < 4; ++reg) {
                const int m = m0 + wr + i * 16 + quad * 4 + reg;
                const int n = n0 + wc + j * 16 + r16;
                const float v = (acc[i][j][reg] + bias[n]) * oscale;
                if (outmode == 0) {
                    ((float*)out)[(size_t)m * DMODEL + n] = v;
                } else if (outmode == 1) {
                    ((ushort*)out)[((size_t)(m >> 11) * NH + (n >> 6)) * (SEQ * DKH)
                                   + (size_t)(m & (SEQ - 1)) * DKH + (n & 63)] = f2bf(v);
                } else {
                    ((ushort*)out)[(((size_t)(m >> 11) * NH + (n >> 6)) * DKH + (n & 63)) * SEQ
                                   + (m & (SEQ - 1))] = f2bf(v);
                }
            }
        }
    }
}

// MFMA flash attention R20b (verified best): REGISTER-DIRECT PV via
// v_mfma_f32_16x16x16_bf16. Swapped-QK^T score layout IS the K=16 MFMA
// A-frag layout -> P never touches LDS. Carried: 512 thr / 128 q-rows, LPT,
// peeled diag, reg prefetch (T14), setprio (T5), exp2 w/ folded scale,
// XCD swizzle.
__global__ __launch_bounds__(512, 4)
void attn_flash(ushort* __restrict__ Qh,
                const ushort* __restrict__ Kh,
                const ushort* __restrict__ VT)
{
    __shared__ ushort Kl[128][72];      // 18432 B
    __shared__ ushort Vl[64][136];      // 17408 B

    const int t512 = threadIdx.x;
    const int wave = t512 >> 6;          // 0..7
    const int lane = t512 & 63;
    const int quad = lane >> 4;
    const int r16  = lane & 15;

    // XCD swizzle (same-head blocks share blockIdx&7) + LPT (heavy qt first)
    const int slot = blockIdx.x & 7;
    const int bh   = slot * 4 + ((blockIdx.x >> 3) & 3);
    const int qt   = 15 - (blockIdx.x >> 5);
    const int q0   = qt * 128;

    ushort*       Qbase = Qh + (size_t)bh * SEQ * DKH;
    const ushort* Kbase = Kh + (size_t)bh * SEQ * DKH;
    const ushort* Vbase = VT + (size_t)bh * DKH * SEQ;

    short8 qf[2];
    {
        const ushort* qrow = Qbase + (size_t)(q0 + wave * 16 + r16) * DKH;
        qf[0] = *(const short8*)(qrow + quad * 8);
        qf[1] = *(const short8*)(qrow + 32 + quad * 8);
    }

    f32x4 oacc[4];
    #pragma unroll
    for (int i = 0; i < 4; ++i) oacc[i] = (f32x4){0.f, 0.f, 0.f, 0.f};
    f32x4 lsum4 = (f32x4){0.f, 0.f, 0.f, 0.f};

    const int T    = qt + 1;            // 128-row q-tile aligns with 128-col k-tiles
    const int qrel = wave * 16 + r16;   // q row relative to diag-tile start

    // staging: K 128x64 (16 KB), V 64x128 (16 KB); 32 B per thread each
    const int krow = t512 >> 2, kc = (t512 & 3) * 16;
    const int vrow = t512 >> 3, vc = (t512 & 7) * 16;
    const ushort* kg0 = Kbase + (size_t)krow * DKH + kc;
    const ushort* vg0 = Vbase + (size_t)vrow * SEQ + vc;

    uint4 kr0, kr1, vr0, vr1;
    kr0 = *(const uint4*)(kg0);
    kr1 = *(const uint4*)(kg0 + 8);
    vr0 = *(const uint4*)(vg0);
    vr1 = *(const uint4*)(vg0 + 8);

    // ---------------- main loop: full tiles, mask-free ----------------
    for (int t = 0; t < T - 1; ++t) {
        *(uint4*)&Kl[krow][kc]     = kr0;
        *(uint4*)&Kl[krow][kc + 8] = kr1;
        *(uint4*)&Vl[vrow][vc]     = vr0;
        *(uint4*)&Vl[vrow][vc + 8] = vr1;
        __syncthreads();

        // prefetch next tile; lands during this tile's compute (T14)
        {
            const ushort* kg = kg0 + (size_t)(t + 1) * 128 * DKH;
            kr0 = *(const uint4*)(kg);
            kr1 = *(const uint4*)(kg + 8);
            const ushort* vg = vg0 + (size_t)(t + 1) * 128;
            vr0 = *(const uint4*)(vg);
            vr1 = *(const uint4*)(vg + 8);
        }

        #pragma unroll
        for (int nt = 0; nt < 8; ++nt) {
            // QK^T (swapped): s[reg] = S[k=nt*16+quad*4+reg][q=r16]
            short8 b0 = *(const short8*)&Kl[nt * 16 + r16][quad * 8];
            short8 b1 = *(const short8*)&Kl[nt * 16 + r16][32 + quad * 8];
            f32x4 s = (f32x4){0.f, 0.f, 0.f, 0.f};
            __builtin_amdgcn_s_setprio(1);
            s = __builtin_amdgcn_mfma_f32_16x16x32_bf16(b0, qf[0], s, 0, 0, 0);
            s = __builtin_amdgcn_mfma_f32_16x16x32_bf16(b1, qf[1], s, 0, 0, 0);
            __builtin_amdgcn_s_setprio(0);

            // softmax numerator, packed in-register (A-frag of K=16 MFMA)
            const float e0 = __builtin_amdgcn_exp2f(s[0]);
            const float e1 = __builtin_amdgcn_exp2f(s[1]);
            const float e2 = __builtin_amdgcn_exp2f(s[2]);
            const float e3 = __builtin_amdgcn_exp2f(s[3]);
            lsum4 += (f32x4){e0, e1, e2, e3};
            union { uint2 u; short4v s4; } pw;
            pw.u.x = pk2(e0, e1);
            pw.u.y = pk2(e2, e3);

            // PV: register-direct, K=16 per nt
            __builtin_amdgcn_s_setprio(1);
            #pragma unroll
            for (int ct = 0; ct < 4; ++ct) {
                short4v vb = *(const short4v*)&Vl[ct * 16 + r16][nt * 16 + quad * 4];
                oacc[ct] = mfma_pv16(pw.s4, vb, oacc[ct]);
            }
            __builtin_amdgcn_s_setprio(0);
        }
        __syncthreads();
    }

    // ---------------- peeled diagonal tile ----------------
    {
        *(uint4*)&Kl[krow][kc]     = kr0;
        *(uint4*)&Kl[krow][kc + 8] = kr1;
        *(uint4*)&Vl[vrow][vc]     = vr0;
        *(uint4*)&Vl[vrow][vc + 8] = vr1;
        __syncthreads();

        const int ntmax = wave | 1;     // k-cols touched: [0, (wave|1)*16+15]

        #pragma unroll
        for (int nt = 0; nt < 8; ++nt) {
            if (nt <= ntmax) {
                short8 b0 = *(const short8*)&Kl[nt * 16 + r16][quad * 8];
                short8 b1 = *(const short8*)&Kl[nt * 16 + r16][32 + quad * 8];
                f32x4 s = (f32x4){0.f, 0.f, 0.f, 0.f};
                __builtin_amdgcn_s_setprio(1);
                s = __builtin_amdgcn_mfma_f32_16x16x32_bf16(b0, qf[0], s, 0, 0, 0);
                s = __builtin_amdgcn_mfma_f32_16x16x32_bf16(b1, qf[1], s, 0, 0, 0);
                __builtin_amdgcn_s_setprio(0);

                float e0 = __builtin_amdgcn_exp2f(s[0]);
                float e1 = __builtin_amdgcn_exp2f(s[1]);
                float e2 = __builtin_amdgcn_exp2f(s[2]);
                float e3 = __builtin_amdgcn_exp2f(s[3]);
                const int kbase = nt * 16 + quad * 4;
                if (kbase + 0 > qrel) e0 = 0.f;
                if (kbase + 1 > qrel) e1 = 0.f;
                if (kbase + 2 > qrel) e2 = 0.f;
                if (kbase + 3 > qrel) e3 = 0.f;
                lsum4 += (f32x4){e0, e1, e2, e3};
                union { uint2 u; short4v s4; } pw;
                pw.u.x = pk2(e0, e1);
                pw.u.y = pk2(e2, e3);

                __builtin_amdgcn_s_setprio(1);
                #pragma unroll
                for (int ct = 0; ct < 4; ++ct) {
                    short4v vb = *(const short4v*)&Vl[ct * 16 + r16][nt * 16 + quad * 4];
                    oacc[ct] = mfma_pv16(pw.s4, vb, oacc[ct]);
                }
                __builtin_amdgcn_s_setprio(0);
            }
        }
        // no trailing barrier: nothing further touches LDS
    }

    // row-sum: lanes {r16, r16+16, r16+32, r16+48} hold partials for q-row r16
    float lsum = (lsum4[0] + lsum4[1]) + (lsum4[2] + lsum4[3]);
    lsum += __shfl_xor(lsum, 16, 64);
    lsum += __shfl_xor(lsum, 32, 64);

    #pragma unroll
    for (int reg = 0; reg < 4; ++reg) {
        // row sum for q-row (quad*4+reg) lives in lane (quad*4+reg)
        const float inv = 1.f / __shfl(lsum, quad * 4 + reg, 64);
        const int q = q0 + wave * 16 + quad * 4 + reg;
        ushort* orow = Qbase + (size_t)q * DKH;
        #pragma unroll
        for (int ct = 0; ct < 4; ++ct)
            orow[ct * 16 + r16] = f2bf(oacc[ct][reg] * inv);
    }
}

extern "C" void kernel_launch(void* const* d_in, const int* in_sizes, int n_in,
                              void* d_out, int out_size, void* d_ws, size_t ws_size,
                              hipStream_t stream)
{
    // Settled: documented dict order; inputs fp32; output fp32; mask unused;
    // ws >= 24 MiB.
    const float* x  = (const float*)d_in[0];
    const float* Wf[4] = {(const float*)d_in[2], (const float*)d_in[4],
                          (const float*)d_in[6], (const float*)d_in[8]};
    const float* Bf[4] = {(const float*)d_in[3], (const float*)d_in[5],
                          (const float*)d_in[7], (const float*)d_in[9]};

    const size_t HSZ = (size_t)MROWS * DMODEL;
    ushort* Qh = (ushort*)d_ws;
    ushort* Kh = (ushort*)d_out;
    ushort* VT = (ushort*)d_out + HSZ;

    const dim3 blk(256);

    if (ws_size >= 24u * 1024 * 1024) {
        ushort* Wcat = Qh + HSZ;
        ushort* Wo   = Wcat + 3 * (size_t)WELEM;
        ushort* xbf  = Wo + WELEM;

        cvt_all<<<dim3(4096), blk, 0, stream>>>(x, Wf[0], Wf[1], Wf[2], Wf[3],
                                                xbf, Wcat, Wo);

        gemm_qkv<<<dim3(3 * DMODEL / 128, MROWS / 128), blk, 0, stream>>>(
            xbf, Wcat, Bf[0], Bf[1], Bf[2], Qh, Kh, VT);

        attn_flash<<<dim3(BSZ * NH * 16), dim3(512), 0, stream>>>(Qh, Kh, VT);

        gemm_out<<<dim3(DMODEL / 64, MROWS / 128), blk, 0, stream>>>(
            Qh, Wo, Bf[3], (float*)d_out);
    } else {
        const dim3 gg(DMODEL / 128, MROWS / 128);
        gemm_mfma<<<gg, blk, 0, stream>>>(x, Wf[0], Bf[0], Qh, 0, 0, 1, 0.18033688f);
        gemm_mfma<<<gg, blk, 0, stream>>>(x, Wf[1], Bf[1], Kh, 0, 0, 1, 1.0f);
        gemm_mfma<<<gg, blk, 0, stream>>>(x, Wf[2], Bf[2], VT, 0, 0, 2, 1.0f);
        attn_flash<<<dim3(BSZ * NH * 16), dim3(512), 0, stream>>>(Qh, Kh, VT);
        gemm_mfma<<<gg, blk, 0, stream>>>(Qh, Wf[3], Bf[3], d_out, 1, 0, 0, 1.0f);
    }
}